// Round 1
// baseline (280.769 us; speedup 1.0000x reference)
//
#include <hip/hip_runtime.h>
#include <math.h>

#define BN_EPS 1e-5f

constexpr int B_ = 4, N_ = 16384, C_ = 64, K_ = 16, O_ = 64;
constexpr int ROWS = B_ * N_;            // 65536
constexpr int ROWS_PER_BLK = 64;
constexpr int NBLK_AB = ROWS / ROWS_PER_BLK; // 1024

// ---------------------------------------------------------------------------
// Pass A: y1[r][o] = x[r]·(W1[o]-W2[o]),  y2[r][o] = x[r]·W2[o]
// block = 256 threads = 64 channels x 4 row-lanes; 64 rows per block.
// ---------------------------------------------------------------------------
__global__ __launch_bounds__(256) void pass_a(const float* __restrict__ x,
                                              const float* __restrict__ w,
                                              float* __restrict__ y1,
                                              float* __restrict__ y2) {
    __shared__ float w1m[64 * 64];  // [c][o] = W1-W2 transposed
    __shared__ float w2s[64 * 64];  // [c][o] = W2 transposed
    __shared__ float xs[64 * 64];   // [r][c]
    const int tid = threadIdx.x;

    for (int i = tid; i < 64 * 64; i += 256) {
        int o = i >> 6, c = i & 63;
        float a = w[o * 128 + c];        // W1[o][c]
        float b = w[o * 128 + 64 + c];   // W2[o][c]
        w1m[c * 64 + o] = a - b;
        w2s[c * 64 + o] = b;
    }
    const long base = (long)blockIdx.x * ROWS_PER_BLK;
    const float* xsrc = x + base * 64;
    for (int i = tid; i < 64 * 64; i += 256) xs[i] = xsrc[i];
    __syncthreads();

    const int o  = tid & 63;
    const int rr = tid >> 6;  // 0..3
    // 4 chunks x 4 rows each = 16 rows per thread-lane-group covering 64 rows
    for (int chunk = 0; chunk < 4; ++chunk) {
        const int r0 = chunk * 16 + rr * 4;
        float a1[4] = {0.f, 0.f, 0.f, 0.f};
        float a2[4] = {0.f, 0.f, 0.f, 0.f};
        for (int c = 0; c < 64; ++c) {
            float wv1 = w1m[c * 64 + o];
            float wv2 = w2s[c * 64 + o];
#pragma unroll
            for (int j = 0; j < 4; ++j) {
                float xv = xs[(r0 + j) * 64 + c];  // wave-uniform -> broadcast
                a1[j] = fmaf(xv, wv1, a1[j]);
                a2[j] = fmaf(xv, wv2, a2[j]);
            }
        }
#pragma unroll
        for (int j = 0; j < 4; ++j) {
            y1[(base + r0 + j) * 64 + o] = a1[j];
            y2[(base + r0 + j) * 64 + o] = a2[j];
        }
    }
}

// ---------------------------------------------------------------------------
// Pass B: h = y1[row][o] + y2[b][idx][o]; per-row max/min over k;
//         per-channel block partial sum / sumsq (deterministic, no atomics).
// ---------------------------------------------------------------------------
__global__ __launch_bounds__(256) void pass_b(const float* __restrict__ y1,
                                              const float* __restrict__ y2,
                                              const int* __restrict__ idx,
                                              float* __restrict__ maxh,
                                              float* __restrict__ minh,
                                              float* __restrict__ partial) {
    __shared__ int sidx[ROWS_PER_BLK * K_];  // 1024 ints
    __shared__ float red[512];
    const int tid = threadIdx.x;
    const long base = (long)blockIdx.x * ROWS_PER_BLK;

    // cooperative idx load: 1024 ints = one int4 per thread (16B aligned)
    ((int4*)sidx)[tid] = ((const int4*)(idx + base * K_))[tid];
    __syncthreads();

    const int o  = tid & 63;
    const int rr = tid >> 6;
    const int b  = (int)(base >> 14);  // 16384 rows per batch; blocks never straddle
    const float* y2b = y2 + (long)b * N_ * 64;

    float sum = 0.f, sumsq = 0.f;
    for (int it = 0; it < 16; ++it) {
        const int rl = it * 4 + rr;
        const long row = base + rl;
        const float y1v = y1[row * 64 + o];
        float hmax = -3.402823466e+38f, hmin = 3.402823466e+38f;
#pragma unroll
        for (int k = 0; k < K_; ++k) {
            int m = sidx[rl * K_ + k];             // wave-uniform -> broadcast
            float h = y1v + y2b[(long)m * 64 + o]; // coalesced 256B gather
            hmax = fmaxf(hmax, h);
            hmin = fminf(hmin, h);
            sum += h;
            sumsq = fmaf(h, h, sumsq);
        }
        maxh[row * 64 + o] = hmax;
        minh[row * 64 + o] = hmin;
    }
    red[tid] = sum;
    red[256 + tid] = sumsq;
    __syncthreads();
    if (rr == 0) {
        float s = red[o] + red[64 + o] + red[128 + o] + red[192 + o];
        float q = red[256 + o] + red[320 + o] + red[384 + o] + red[448 + o];
        partial[blockIdx.x * 128 + o] = s;
        partial[blockIdx.x * 128 + 64 + o] = q;
    }
}

// ---------------------------------------------------------------------------
// Pass C: reduce 1024 partials per column (double), produce scale/shift.
// ---------------------------------------------------------------------------
__global__ __launch_bounds__(256) void pass_c(const float* __restrict__ partial,
                                              const float* __restrict__ gamma,
                                              const float* __restrict__ beta,
                                              float* __restrict__ ss) {
    __shared__ double tmp[256];
    __shared__ double tot[128];
    const int tid = threadIdx.x;
    const int col = tid & 127;
    const int half = tid >> 7;
    double acc = 0.0;
    for (int j = half * 512; j < half * 512 + 512; ++j)
        acc += (double)partial[j * 128 + col];
    tmp[tid] = acc;
    __syncthreads();
    if (half == 0) tot[col] = tmp[col] + tmp[128 + col];
    __syncthreads();
    if (tid < 64) {
        const double cnt = (double)B_ * N_ * K_;  // 1,048,576
        double mean = tot[tid] / cnt;
        double var = tot[64 + tid] / cnt - mean * mean;
        float scale = gamma[tid] * (float)(1.0 / sqrt(var + (double)BN_EPS));
        float shift = beta[tid] - (float)mean * scale;
        ss[tid] = scale;
        ss[64 + tid] = shift;
    }
}

// ---------------------------------------------------------------------------
// Pass D: out = relu(scale * ext + shift); ext = scale>=0 ? maxh : minh
// (max_k commutes with positive affine; min_k with negative; relu monotone)
// ---------------------------------------------------------------------------
__global__ __launch_bounds__(256) void pass_d(const float* __restrict__ maxh,
                                              const float* __restrict__ minh,
                                              const float* __restrict__ ss,
                                              float* __restrict__ out) {
    __shared__ float sscale[64], sshift[64];
    const int tid = threadIdx.x;
    if (tid < 64) { sscale[tid] = ss[tid]; sshift[tid] = ss[64 + tid]; }
    __syncthreads();
    const float4* mx = (const float4*)maxh;
    const float4* mn = (const float4*)minh;
    float4* op = (float4*)out;
    const long total4 = (long)ROWS * 64 / 4;  // 1,048,576
    for (long i = (long)blockIdx.x * 256 + tid; i < total4;
         i += (long)gridDim.x * 256) {
        const int c0 = ((int)i * 4) & 63;
        float4 a = mx[i];
        float4 b = mn[i];
        float s0 = sscale[c0],     s1 = sscale[c0 + 1];
        float s2 = sscale[c0 + 2], s3 = sscale[c0 + 3];
        float e0 = (s0 >= 0.f) ? a.x : b.x;
        float e1 = (s1 >= 0.f) ? a.y : b.y;
        float e2 = (s2 >= 0.f) ? a.z : b.z;
        float e3 = (s3 >= 0.f) ? a.w : b.w;
        float4 r;
        r.x = fmaxf(fmaf(s0, e0, sshift[c0]),     0.f);
        r.y = fmaxf(fmaf(s1, e1, sshift[c0 + 1]), 0.f);
        r.z = fmaxf(fmaf(s2, e2, sshift[c0 + 2]), 0.f);
        r.w = fmaxf(fmaf(s3, e3, sshift[c0 + 3]), 0.f);
        op[i] = r;
    }
}

extern "C" void kernel_launch(void* const* d_in, const int* in_sizes, int n_in,
                              void* d_out, int out_size, void* d_ws, size_t ws_size,
                              hipStream_t stream) {
    const float* x     = (const float*)d_in[0];
    const int*   idx   = (const int*)d_in[1];
    const float* w     = (const float*)d_in[2];
    const float* gamma = (const float*)d_in[3];
    const float* beta  = (const float*)d_in[4];
    float* out = (float*)d_out;

    float* ws = (float*)d_ws;
    float* y1      = ws;                                 // 65536*64
    float* y2      = y1 + (long)ROWS * 64;               // 65536*64
    float* maxh    = y2 + (long)ROWS * 64;               // 65536*64
    float* minh    = maxh + (long)ROWS * 64;             // 65536*64
    float* partial = minh + (long)ROWS * 64;             // 1024*128
    float* ss      = partial + (long)NBLK_AB * 128;      // 128

    pass_a<<<NBLK_AB, 256, 0, stream>>>(x, w, y1, y2);
    pass_b<<<NBLK_AB, 256, 0, stream>>>(y1, y2, idx, maxh, minh, partial);
    pass_c<<<1, 256, 0, stream>>>(partial, gamma, beta, ss);
    pass_d<<<2048, 256, 0, stream>>>(maxh, minh, ss, out);
}

// Round 2
// 154.351 us; speedup vs baseline: 1.8190x; 1.8190x over previous
//
#include <hip/hip_runtime.h>
#include <math.h>

#define BN_EPS 1e-5f

constexpr int B_ = 4, N_ = 16384, C_ = 64, K_ = 16, O_ = 64;
constexpr int ROWS = B_ * N_;            // 65536
constexpr int ROWS_PER_BLK = 64;
constexpr int NBLK_AB = ROWS / ROWS_PER_BLK; // 1024

// ---------------------------------------------------------------------------
// Pass A: y1[r][o] = x[r]·(W1[o]-W2[o]),  y2[r][o] = x[r]·W2[o]
// block = 256 threads = 64 channels x 4 row-lanes; 64 rows per block.
// ---------------------------------------------------------------------------
__global__ __launch_bounds__(256) void pass_a(const float* __restrict__ x,
                                              const float* __restrict__ w,
                                              float* __restrict__ y1,
                                              float* __restrict__ y2) {
    __shared__ float w1m[64 * 64];  // [c][o] = W1-W2 transposed
    __shared__ float w2s[64 * 64];  // [c][o] = W2 transposed
    __shared__ float xs[64 * 64];   // [r][c]
    const int tid = threadIdx.x;

    for (int i = tid; i < 64 * 64; i += 256) {
        int o = i >> 6, c = i & 63;
        float a = w[o * 128 + c];        // W1[o][c]
        float b = w[o * 128 + 64 + c];   // W2[o][c]
        w1m[c * 64 + o] = a - b;
        w2s[c * 64 + o] = b;
    }
    const long base = (long)blockIdx.x * ROWS_PER_BLK;
    const float* xsrc = x + base * 64;
    for (int i = tid; i < 64 * 64; i += 256) xs[i] = xsrc[i];
    __syncthreads();

    const int o  = tid & 63;
    const int rr = tid >> 6;  // 0..3
    for (int chunk = 0; chunk < 4; ++chunk) {
        const int r0 = chunk * 16 + rr * 4;
        float a1[4] = {0.f, 0.f, 0.f, 0.f};
        float a2[4] = {0.f, 0.f, 0.f, 0.f};
        for (int c = 0; c < 64; ++c) {
            float wv1 = w1m[c * 64 + o];
            float wv2 = w2s[c * 64 + o];
#pragma unroll
            for (int j = 0; j < 4; ++j) {
                float xv = xs[(r0 + j) * 64 + c];  // wave-uniform -> broadcast
                a1[j] = fmaf(xv, wv1, a1[j]);
                a2[j] = fmaf(xv, wv2, a2[j]);
            }
        }
#pragma unroll
        for (int j = 0; j < 4; ++j) {
            y1[(base + r0 + j) * 64 + o] = a1[j];
            y2[(base + r0 + j) * 64 + o] = a2[j];
        }
    }
}

// ---------------------------------------------------------------------------
// Pass B: h = y1[row][o] + y2[b][idx][o]; per-row signed extremum over k
// (gamma sign known up front: scale = gamma*rsqrt(var+eps) has sign(gamma),
//  so only the relevant extremum is needed); per-channel block partials.
// ---------------------------------------------------------------------------
__global__ __launch_bounds__(256) void pass_b(const float* __restrict__ y1,
                                              const float* __restrict__ y2,
                                              const int* __restrict__ idx,
                                              const float* __restrict__ gamma,
                                              float* __restrict__ exth,
                                              float* __restrict__ partial) {
    __shared__ int sidx[ROWS_PER_BLK * K_];  // 1024 ints
    __shared__ float red[512];
    const int tid = threadIdx.x;
    const long base = (long)blockIdx.x * ROWS_PER_BLK;

    // cooperative idx load: 1024 ints = one int4 per thread (16B aligned)
    ((int4*)sidx)[tid] = ((const int4*)(idx + base * K_))[tid];

    const int o  = tid & 63;
    const int rr = tid >> 6;
    const bool pos = (gamma[o] >= 0.f);
    const int b  = (int)(base >> 14);  // 16384 rows/batch; blocks never straddle
    const float* y2b = y2 + (long)b * N_ * 64;
    __syncthreads();

    float sum = 0.f, sumsq = 0.f;
    for (int it = 0; it < 16; ++it) {
        const int rl = it * 4 + rr;
        const long row = base + rl;
        const float y1v = y1[row * 64 + o];
        float hmax = -3.402823466e+38f, hmin = 3.402823466e+38f;
#pragma unroll
        for (int k = 0; k < K_; ++k) {
            int m = sidx[rl * K_ + k];             // wave-uniform -> broadcast
            float h = y1v + y2b[(long)m * 64 + o]; // coalesced 256B gather
            hmax = fmaxf(hmax, h);
            hmin = fminf(hmin, h);
            sum += h;
            sumsq = fmaf(h, h, sumsq);
        }
        exth[row * 64 + o] = pos ? hmax : hmin;
    }
    red[tid] = sum;
    red[256 + tid] = sumsq;
    __syncthreads();
    if (rr == 0) {
        float s = red[o] + red[64 + o] + red[128 + o] + red[192 + o];
        float q = red[256 + o] + red[320 + o] + red[384 + o] + red[448 + o];
        partial[blockIdx.x * 128 + o] = s;
        partial[blockIdx.x * 128 + 64 + o] = q;
    }
}

// ---------------------------------------------------------------------------
// Pass C: 64 blocks, one per channel. Block o reduces sum (col o) and sumsq
// (col 64+o) over the 1024 block-partials in double, emits scale/shift.
// ---------------------------------------------------------------------------
__global__ __launch_bounds__(256) void pass_c(const float* __restrict__ partial,
                                              const float* __restrict__ gamma,
                                              const float* __restrict__ beta,
                                              float* __restrict__ ss) {
    __shared__ double rs[256];
    __shared__ double rq[256];
    const int o = blockIdx.x;
    const int tid = threadIdx.x;
    double as = 0.0, aq = 0.0;
    for (int i = tid; i < NBLK_AB; i += 256) {
        as += (double)partial[i * 128 + o];
        aq += (double)partial[i * 128 + 64 + o];
    }
    rs[tid] = as;
    rq[tid] = aq;
    __syncthreads();
    for (int s = 128; s > 0; s >>= 1) {
        if (tid < s) { rs[tid] += rs[tid + s]; rq[tid] += rq[tid + s]; }
        __syncthreads();
    }
    if (tid == 0) {
        const double cnt = (double)B_ * N_ * K_;  // 1,048,576
        double mean = rs[0] / cnt;
        double var = rq[0] / cnt - mean * mean;
        float scale = gamma[o] * (float)(1.0 / sqrt(var + (double)BN_EPS));
        float shift = beta[o] - (float)mean * scale;
        ss[o] = scale;
        ss[64 + o] = shift;
    }
}

// ---------------------------------------------------------------------------
// Pass D: out = relu(scale * exth + shift)  (sign already folded into exth)
// ---------------------------------------------------------------------------
__global__ __launch_bounds__(256) void pass_d(const float* __restrict__ exth,
                                              const float* __restrict__ ss,
                                              float* __restrict__ out) {
    __shared__ float sscale[64], sshift[64];
    const int tid = threadIdx.x;
    if (tid < 64) { sscale[tid] = ss[tid]; sshift[tid] = ss[64 + tid]; }
    __syncthreads();
    const float4* ep = (const float4*)exth;
    float4* op = (float4*)out;
    const long total4 = (long)ROWS * 64 / 4;  // 1,048,576
    for (long i = (long)blockIdx.x * 256 + tid; i < total4;
         i += (long)gridDim.x * 256) {
        const int c0 = ((int)i * 4) & 63;
        float4 e = ep[i];
        float4 r;
        r.x = fmaxf(fmaf(sscale[c0],     e.x, sshift[c0]),     0.f);
        r.y = fmaxf(fmaf(sscale[c0 + 1], e.y, sshift[c0 + 1]), 0.f);
        r.z = fmaxf(fmaf(sscale[c0 + 2], e.z, sshift[c0 + 2]), 0.f);
        r.w = fmaxf(fmaf(sscale[c0 + 3], e.w, sshift[c0 + 3]), 0.f);
        op[i] = r;
    }
}

extern "C" void kernel_launch(void* const* d_in, const int* in_sizes, int n_in,
                              void* d_out, int out_size, void* d_ws, size_t ws_size,
                              hipStream_t stream) {
    const float* x     = (const float*)d_in[0];
    const int*   idx   = (const int*)d_in[1];
    const float* w     = (const float*)d_in[2];
    const float* gamma = (const float*)d_in[3];
    const float* beta  = (const float*)d_in[4];
    float* out = (float*)d_out;

    float* ws = (float*)d_ws;
    float* y1      = ws;                                 // 65536*64
    float* y2      = y1 + (long)ROWS * 64;               // 65536*64
    float* exth    = y2 + (long)ROWS * 64;               // 65536*64
    float* partial = exth + (long)ROWS * 64;             // 1024*128
    float* ss      = partial + (long)NBLK_AB * 128;      // 128

    pass_a<<<NBLK_AB, 256, 0, stream>>>(x, w, y1, y2);
    pass_b<<<NBLK_AB, 256, 0, stream>>>(y1, y2, idx, gamma, exth, partial);
    pass_c<<<64, 256, 0, stream>>>(partial, gamma, beta, ss);
    pass_d<<<2048, 256, 0, stream>>>(exth, ss, out);
}

// Round 3
// 125.371 us; speedup vs baseline: 2.2395x; 1.2312x over previous
//
#include <hip/hip_runtime.h>
#include <math.h>

#define BN_EPS 1e-5f

constexpr int B_ = 4, N_ = 16384, C_ = 64, K_ = 16, O_ = 64;
constexpr int ROWS = B_ * N_;            // 65536
constexpr int ROWS_PER_BLK = 64;
constexpr int NBLK_AB = ROWS / ROWS_PER_BLK; // 1024

// ---------------------------------------------------------------------------
// Pass A: y1[r][o] = x[r]·(W1[o]-W2[o]),  y2[r][o] = x[r]·W2[o]
// Transposed weight tiles padded to stride 65: write banks (c+o)%32 (2-way,
// free) instead of o%32 (64-way). xs inner reads vectorized to float4.
// ---------------------------------------------------------------------------
__global__ __launch_bounds__(256) void pass_a(const float* __restrict__ x,
                                              const float* __restrict__ w,
                                              float* __restrict__ y1,
                                              float* __restrict__ y2) {
    __shared__ float w1m[64 * 65];  // [c][o] = (W1-W2)^T, padded
    __shared__ float w2s[64 * 65];  // [c][o] = W2^T, padded
    __shared__ float xs[64 * 64];   // [r][c]
    const int tid = threadIdx.x;

    for (int i = tid; i < 64 * 64; i += 256) {
        int o = i >> 6, c = i & 63;
        float a = w[o * 128 + c];        // W1[o][c]
        float b = w[o * 128 + 64 + c];   // W2[o][c]
        w1m[c * 65 + o] = a - b;
        w2s[c * 65 + o] = b;
    }
    const long base = (long)blockIdx.x * ROWS_PER_BLK;
    const float* xsrc = x + base * 64;
    for (int i = tid; i < 64 * 64; i += 256) xs[i] = xsrc[i];
    __syncthreads();

    const int o  = tid & 63;
    const int rr = tid >> 6;  // 0..3
    for (int chunk = 0; chunk < 4; ++chunk) {
        const int r0 = chunk * 16 + rr * 4;
        float a1[4] = {0.f, 0.f, 0.f, 0.f};
        float a2[4] = {0.f, 0.f, 0.f, 0.f};
        for (int c4 = 0; c4 < 16; ++c4) {
            float4 xv[4];
#pragma unroll
            for (int j = 0; j < 4; ++j)
                xv[j] = *(const float4*)&xs[(r0 + j) * 64 + c4 * 4];
#pragma unroll
            for (int cc = 0; cc < 4; ++cc) {
                const int c = c4 * 4 + cc;
                const float wv1 = w1m[c * 65 + o];
                const float wv2 = w2s[c * 65 + o];
                const float xj0 = (&xv[0].x)[cc], xj1 = (&xv[1].x)[cc];
                const float xj2 = (&xv[2].x)[cc], xj3 = (&xv[3].x)[cc];
                a1[0] = fmaf(xj0, wv1, a1[0]); a2[0] = fmaf(xj0, wv2, a2[0]);
                a1[1] = fmaf(xj1, wv1, a1[1]); a2[1] = fmaf(xj1, wv2, a2[1]);
                a1[2] = fmaf(xj2, wv1, a1[2]); a2[2] = fmaf(xj2, wv2, a2[2]);
                a1[3] = fmaf(xj3, wv1, a1[3]); a2[3] = fmaf(xj3, wv2, a2[3]);
            }
        }
#pragma unroll
        for (int j = 0; j < 4; ++j) {
            y1[(base + r0 + j) * 64 + o] = a1[j];
            y2[(base + r0 + j) * 64 + o] = a2[j];
        }
    }
}

// ---------------------------------------------------------------------------
// Pass B: h = y1[row] + y2[b][idx]; per-row signed extremum over k=16 and
// per-channel partials. Lane layout: lane = ksub*16 + c4 (4 k-groups x 16
// channel-quads), float4 gathers (1 KiB per wave-instr). k-reduction via
// __shfl_xor(16/32). gamma sign folded: e = s*h, butterfly max, ext = s*e.
// XCD-affine block remap: batch = (blk%8)>>1 so each XCD's gathers stay in
// one 4.2 MB y2 slice (~its private L2).
// ---------------------------------------------------------------------------
__global__ __launch_bounds__(256) void pass_b(const float* __restrict__ y1,
                                              const float* __restrict__ y2,
                                              const int* __restrict__ idx,
                                              const float* __restrict__ gamma,
                                              float* __restrict__ exth,
                                              float* __restrict__ partial) {
    __shared__ int sidx[ROWS_PER_BLK * K_];  // 1024 ints
    __shared__ float reds[4][64];
    __shared__ float redq[4][64];
    const int tid = threadIdx.x;
    const int blk = blockIdx.x;
    const int xcd = blk & 7;
    const int bt = xcd >> 1;                         // batch for this XCD pair
    const int slot = ((blk >> 3) << 1) | (xcd & 1);  // 0..255 within batch
    const long base = (long)bt * N_ + (long)slot * ROWS_PER_BLK;

    ((int4*)sidx)[tid] = ((const int4*)(idx + base * K_))[tid];

    const int lane = tid & 63;
    const int wv   = tid >> 6;   // wave 0..3
    const int ksub = lane >> 4;  // 0..3
    const int c4   = lane & 15;  // channel quad: channels 4*c4..4*c4+3
    const float* y2b = y2 + (long)bt * N_ * 64;

    const float4 gm = ((const float4*)gamma)[c4];
    const float4 sgn = make_float4(gm.x >= 0.f ? 1.f : -1.f,
                                   gm.y >= 0.f ? 1.f : -1.f,
                                   gm.z >= 0.f ? 1.f : -1.f,
                                   gm.w >= 0.f ? 1.f : -1.f);
    __syncthreads();

    float4 psum = make_float4(0.f, 0.f, 0.f, 0.f);
    float4 psq  = make_float4(0.f, 0.f, 0.f, 0.f);

    for (int rl = wv; rl < ROWS_PER_BLK; rl += 4) {  // 16 rows per wave
        const long row = base + rl;
        const float4 y1v = ((const float4*)(y1 + row * 64))[c4];
        float4 e = make_float4(-3.402823466e+38f, -3.402823466e+38f,
                               -3.402823466e+38f, -3.402823466e+38f);
#pragma unroll
        for (int kk = 0; kk < 4; ++kk) {
            const int m = sidx[rl * K_ + kk * 4 + ksub];
            const float4 v = *(const float4*)(y2b + (long)m * 64 + c4 * 4);
            const float hx = y1v.x + v.x, hy = y1v.y + v.y;
            const float hz = y1v.z + v.z, hw = y1v.w + v.w;
            e.x = fmaxf(e.x, sgn.x * hx); e.y = fmaxf(e.y, sgn.y * hy);
            e.z = fmaxf(e.z, sgn.z * hz); e.w = fmaxf(e.w, sgn.w * hw);
            psum.x += hx; psum.y += hy; psum.z += hz; psum.w += hw;
            psq.x = fmaf(hx, hx, psq.x); psq.y = fmaf(hy, hy, psq.y);
            psq.z = fmaf(hz, hz, psq.z); psq.w = fmaf(hw, hw, psq.w);
        }
        // reduce over the 4 ksub groups (lanes 16 apart)
#pragma unroll
        for (int d = 16; d <= 32; d <<= 1) {
            e.x = fmaxf(e.x, __shfl_xor(e.x, d));
            e.y = fmaxf(e.y, __shfl_xor(e.y, d));
            e.z = fmaxf(e.z, __shfl_xor(e.z, d));
            e.w = fmaxf(e.w, __shfl_xor(e.w, d));
        }
        if (ksub == 0) {
            float4 r = make_float4(sgn.x * e.x, sgn.y * e.y,
                                   sgn.z * e.z, sgn.w * e.w);
            *(float4*)(exth + row * 64 + c4 * 4) = r;
        }
    }
    // reduce per-lane partial sums over ksub groups
#pragma unroll
    for (int d = 16; d <= 32; d <<= 1) {
        psum.x += __shfl_xor(psum.x, d); psum.y += __shfl_xor(psum.y, d);
        psum.z += __shfl_xor(psum.z, d); psum.w += __shfl_xor(psum.w, d);
        psq.x  += __shfl_xor(psq.x, d);  psq.y  += __shfl_xor(psq.y, d);
        psq.z  += __shfl_xor(psq.z, d);  psq.w  += __shfl_xor(psq.w, d);
    }
    if (ksub == 0) {
        *(float4*)&reds[wv][c4 * 4] = psum;
        *(float4*)&redq[wv][c4 * 4] = psq;
    }
    __syncthreads();
    if (tid < 64) {
        const float s = reds[0][tid] + reds[1][tid] + reds[2][tid] + reds[3][tid];
        const float q = redq[0][tid] + redq[1][tid] + redq[2][tid] + redq[3][tid];
        partial[blk * 128 + tid] = s;
        partial[blk * 128 + 64 + tid] = q;
    }
}

// ---------------------------------------------------------------------------
// Pass C: 64 blocks, one per channel; double-precision reduction of the
// 1024 block partials; emits scale/shift.
// ---------------------------------------------------------------------------
__global__ __launch_bounds__(256) void pass_c(const float* __restrict__ partial,
                                              const float* __restrict__ gamma,
                                              const float* __restrict__ beta,
                                              float* __restrict__ ss) {
    __shared__ double rs[256];
    __shared__ double rq[256];
    const int o = blockIdx.x;
    const int tid = threadIdx.x;
    double as = 0.0, aq = 0.0;
    for (int i = tid; i < NBLK_AB; i += 256) {
        as += (double)partial[i * 128 + o];
        aq += (double)partial[i * 128 + 64 + o];
    }
    rs[tid] = as;
    rq[tid] = aq;
    __syncthreads();
    for (int s = 128; s > 0; s >>= 1) {
        if (tid < s) { rs[tid] += rs[tid + s]; rq[tid] += rq[tid + s]; }
        __syncthreads();
    }
    if (tid == 0) {
        const double cnt = (double)B_ * N_ * K_;  // 1,048,576
        double mean = rs[0] / cnt;
        double var = rq[0] / cnt - mean * mean;
        float scale = gamma[o] * (float)(1.0 / sqrt(var + (double)BN_EPS));
        float shift = beta[o] - (float)mean * scale;
        ss[o] = scale;
        ss[64 + o] = shift;
    }
}

// ---------------------------------------------------------------------------
// Pass D: out = relu(scale * exth + shift)  (sign already folded into exth)
// ---------------------------------------------------------------------------
__global__ __launch_bounds__(256) void pass_d(const float* __restrict__ exth,
                                              const float* __restrict__ ss,
                                              float* __restrict__ out) {
    __shared__ float sscale[64], sshift[64];
    const int tid = threadIdx.x;
    if (tid < 64) { sscale[tid] = ss[tid]; sshift[tid] = ss[64 + tid]; }
    __syncthreads();
    const float4* ep = (const float4*)exth;
    float4* op = (float4*)out;
    const long total4 = (long)ROWS * 64 / 4;  // 1,048,576
    for (long i = (long)blockIdx.x * 256 + tid; i < total4;
         i += (long)gridDim.x * 256) {
        const int c0 = ((int)i * 4) & 63;
        float4 e = ep[i];
        float4 r;
        r.x = fmaxf(fmaf(sscale[c0],     e.x, sshift[c0]),     0.f);
        r.y = fmaxf(fmaf(sscale[c0 + 1], e.y, sshift[c0 + 1]), 0.f);
        r.z = fmaxf(fmaf(sscale[c0 + 2], e.z, sshift[c0 + 2]), 0.f);
        r.w = fmaxf(fmaf(sscale[c0 + 3], e.w, sshift[c0 + 3]), 0.f);
        op[i] = r;
    }
}

extern "C" void kernel_launch(void* const* d_in, const int* in_sizes, int n_in,
                              void* d_out, int out_size, void* d_ws, size_t ws_size,
                              hipStream_t stream) {
    const float* x     = (const float*)d_in[0];
    const int*   idx   = (const int*)d_in[1];
    const float* w     = (const float*)d_in[2];
    const float* gamma = (const float*)d_in[3];
    const float* beta  = (const float*)d_in[4];
    float* out = (float*)d_out;

    float* ws = (float*)d_ws;
    float* y1      = ws;                                 // 65536*64
    float* y2      = y1 + (long)ROWS * 64;               // 65536*64
    float* exth    = y2 + (long)ROWS * 64;               // 65536*64
    float* partial = exth + (long)ROWS * 64;             // 1024*128
    float* ss      = partial + (long)NBLK_AB * 128;      // 128

    pass_a<<<NBLK_AB, 256, 0, stream>>>(x, w, y1, y2);
    pass_b<<<NBLK_AB, 256, 0, stream>>>(y1, y2, idx, gamma, exth, partial);
    pass_c<<<64, 256, 0, stream>>>(partial, gamma, beta, ss);
    pass_d<<<2048, 256, 0, stream>>>(exth, ss, out);
}